// Round 14
// baseline (129.775 us; speedup 1.0000x reference)
//
#include <hip/hip_runtime.h>
#include <math.h>

// Dims (fixed by the problem)
#define B_SZ 2
#define L_SZ 384
#define D_SZ 384
#define S_SZ 384
#define BLK_ELEMS (L_SZ * D_SZ)        // 147456 per batch
#define TOT_ELEMS (B_SZ * L_SZ * D_SZ) // 294912
#define LOG2E 1.4426950408889634f

typedef __attribute__((ext_vector_type(8))) short bf16x8;
typedef __attribute__((ext_vector_type(4))) float f32x4;
typedef __attribute__((ext_vector_type(2))) unsigned int u32x2;

__device__ __forceinline__ float fexp2(float x) {
  return __builtin_amdgcn_exp2f(x);
}
__device__ __forceinline__ float softplus_f(float z) {
  return (z > 20.f) ? z : log1pf(__expf(z));
}
__device__ __forceinline__ unsigned short f2bf(float f) {  // RNE f32->bf16
  unsigned int u = __float_as_uint(f);
  return (unsigned short)((u + 0x7FFFu + ((u >> 16) & 1u)) >> 16);
}
#define PIPELINE_FENCE() asm volatile("" ::: "memory")

// 8x f32 -> 8x bf16 (RNE) via v_cvt_pk_bf16_f32. SAFE here: inputs come
// from memory loads (counter-based waitcnts cover asm operands). NOT safe
// for MFMA results — the MFMA-dst->VALU-read wait-state hazard is
// invisible through inline asm (v20-22 NaN lesson).
__device__ __forceinline__ bf16x8 cvt8(const float* p) {
  const f32x4 v0 = *(const f32x4*)p;
  const f32x4 v1 = *(const f32x4*)(p + 4);
  union { unsigned int u[4]; bf16x8 v; } r;
  asm("v_cvt_pk_bf16_f32 %0, %1, %2" : "=v"(r.u[0]) : "v"(v0[0]), "v"(v0[1]));
  asm("v_cvt_pk_bf16_f32 %0, %1, %2" : "=v"(r.u[1]) : "v"(v0[2]), "v"(v0[3]));
  asm("v_cvt_pk_bf16_f32 %0, %1, %2" : "=v"(r.u[2]) : "v"(v1[0]), "v"(v1[1]));
  asm("v_cvt_pk_bf16_f32 %0, %1, %2" : "=v"(r.u[3]) : "v"(v1[2]), "v"(v1[3]));
  return r.v;
}

// DPP lane exchange (VALU pipe). CTRL: 0x140=row_mirror (xor15),
// 0x141=row_half_mirror (xor7), 0xB1=quad_perm[1,0,3,2] (xor1),
// 0x4E=quad_perm[2,3,0,1] (xor2).
template <int CTRL>
__device__ __forceinline__ float dpp_mov(float v) {
  return __int_as_float(
      __builtin_amdgcn_update_dpp(0, __float_as_int(v), CTRL, 0xF, 0xF, true));
}

// r + shfl_xor(r,16)/(r,32) in ALL lanes via permlane*_swap BUILTINS
// (raw asm hit the gfx950 VALU-write->permlane wait-state hazard, v13).
__device__ __forceinline__ float fold_xor16(float r) {
#if __has_builtin(__builtin_amdgcn_permlane16_swap)
  const unsigned ru = __float_as_uint(r);
  u32x2 p = __builtin_amdgcn_permlane16_swap(ru, ru, false, false);
  return __uint_as_float(p[0]) + __uint_as_float(p[1]);
#else
  return r + __shfl_xor(r, 16, 64);
#endif
}
__device__ __forceinline__ float fold_xor32(float r) {
#if __has_builtin(__builtin_amdgcn_permlane32_swap)
  const unsigned ru = __float_as_uint(r);
  u32x2 p = __builtin_amdgcn_permlane32_swap(ru, ru, false, false);
  return __uint_as_float(p[0]) + __uint_as_float(p[1]);
#else
  return r + __shfl_xor(r, 32, 64);
#endif
}

// ---------------------------------------------------------------------------
// LDS-staged dual MFMA NT-GEMM. MODE 1: A=f32 (x), O1=softplus dt, O2=xdbl
// bf16 row-major. MODE 2: A=bf16, O1=Bm f32, O2=Cm PACKED u32x2 per
// (l-group of 4, col): {pack(l0,l1), pack(l2,l3)} — packed in PLAIN C via
// f2bf (compiler-visible acc2 reads get the MFMA hazard NOPs; R13-proven).
// ---------------------------------------------------------------------------
template <int MODE>
__global__ __launch_bounds__(128, 2) void mfma_dual_gemm(
    const void* __restrict__ Av, const float* __restrict__ W1,
    const float* __restrict__ W2, const float* __restrict__ bias,
    float* __restrict__ O1, void* __restrict__ O2v) {
  __shared__ unsigned short sA[32 * 392];
  __shared__ unsigned short sW1[16 * 392];
  __shared__ unsigned short sW2[16 * 392];

  const int t = threadIdx.x;
  const int wv = t >> 6;
  const int lane = t & 63;
  const int nt = blockIdx.x;
  const int mrow = blockIdx.y;

  const float* W1b = W1 + nt * 16 * 384;
  const float* W2b = W2 + nt * 16 * 384;

  if constexpr (MODE == 1) {
    const float* Ab = (const float*)Av + mrow * 32 * 384;
#pragma unroll
    for (int it = 0; it < 12; ++it) {
      const int id = t + it * 128;
      const int row = id / 48, col = id - row * 48;
      *(bf16x8*)&sA[row * 392 + col * 8] = cvt8(Ab + id * 8);
    }
  } else {
    const unsigned short* Ab = (const unsigned short*)Av + mrow * 32 * 384;
#pragma unroll
    for (int it = 0; it < 12; ++it) {
      const int id = t + it * 128;
      const int row = id / 48, col = id - row * 48;
      *(bf16x8*)&sA[row * 392 + col * 8] = *(const bf16x8*)(Ab + id * 8);
    }
  }
#pragma unroll
  for (int it = 0; it < 6; ++it) {
    const int id = t + it * 128;
    const int row = id / 48, col = id - row * 48;
    *(bf16x8*)&sW1[row * 392 + col * 8] = cvt8(W1b + id * 8);
    *(bf16x8*)&sW2[row * 392 + col * 8] = cvt8(W2b + id * 8);
  }
  __syncthreads();

  const int rc = lane & 15;
  const int quad = lane >> 4;
  bf16x8 af[12], w1f[12], w2f[12];
#pragma unroll
  for (int kt = 0; kt < 12; ++kt) {
    af[kt] = *(const bf16x8*)&sA[(wv * 16 + rc) * 392 + quad * 8 + kt * 32];
    w1f[kt] = *(const bf16x8*)&sW1[rc * 392 + quad * 8 + kt * 32];
    w2f[kt] = *(const bf16x8*)&sW2[rc * 392 + quad * 8 + kt * 32];
  }
  PIPELINE_FENCE();
  f32x4 acc1 = {0.f, 0.f, 0.f, 0.f};
  f32x4 acc2 = {0.f, 0.f, 0.f, 0.f};
#pragma unroll
  for (int kt = 0; kt < 12; ++kt) {
    acc1 = __builtin_amdgcn_mfma_f32_16x16x32_bf16(af[kt], w1f[kt], acc1, 0, 0, 0);
    acc2 = __builtin_amdgcn_mfma_f32_16x16x32_bf16(af[kt], w2f[kt], acc2, 0, 0, 0);
  }
  const int col = nt * 16 + rc;
  const int row0 = mrow * 32 + wv * 16 + quad * 4;   // multiple of 4
  if constexpr (MODE == 1) {
    unsigned short* O2 = (unsigned short*)O2v;
    const float bb = bias[col];
#pragma unroll
    for (int r = 0; r < 4; ++r) {
      O1[(row0 + r) * 384 + col] = softplus_f(acc1[r] + bb);
      O2[(row0 + r) * 384 + col] = f2bf(acc2[r]);
    }
  } else {
#pragma unroll
    for (int r = 0; r < 4; ++r)
      O1[(row0 + r) * 384 + col] = acc1[r];
    // Plain-C pack (hazard-safe): compiler-emitted reads of acc2 get the
    // required MFMA-read wait states.
    const unsigned int p01 =
        (unsigned int)f2bf(acc2[0]) | ((unsigned int)f2bf(acc2[1]) << 16);
    const unsigned int p23 =
        (unsigned int)f2bf(acc2[2]) | ((unsigned int)f2bf(acc2[3]) << 16);
    u32x2 q = {p01, p23};
    *((u32x2*)O2v + ((row0 >> 2) * 384 + col)) = q;
  }
}

// ---------------------------------------------------------------------------
// Conv + SiLU + transpose (unchanged).
// ---------------------------------------------------------------------------
__global__ __launch_bounds__(256) void conv_tr_kernel(
    const float* __restrict__ x, const float* __restrict__ cw,
    const float* __restrict__ cb, const float* __restrict__ dt,
    float* __restrict__ u, float* __restrict__ dt_t,
    float* __restrict__ dtu_t) {
  __shared__ float Tdt[32][33];
  __shared__ float Tdu[32][33];
  const int tx = threadIdx.x;
  const int ty = threadIdx.y;
  const int b = blockIdx.z;
  const int i0 = blockIdx.y * 32;
  const int l0 = blockIdx.x * 32;
  const int gi = i0 + tx;
  const float cbv = cb[gi];
  const float cw0 = cw[gi * 4 + 0], cw1 = cw[gi * 4 + 1];
  const float cw2 = cw[gi * 4 + 2], cw3 = cw[gi * 4 + 3];
#pragma unroll
  for (int r = 0; r < 4; ++r) {
    const int l = l0 + ty + 8 * r;
    float acc = cbv;
    const float x3 = x[(b * L_SZ + l) * D_SZ + gi];
    const float x2 = (l >= 1) ? x[(b * L_SZ + l - 1) * D_SZ + gi] : 0.f;
    const float x1 = (l >= 2) ? x[(b * L_SZ + l - 2) * D_SZ + gi] : 0.f;
    const float x0 = (l >= 3) ? x[(b * L_SZ + l - 3) * D_SZ + gi] : 0.f;
    acc = fmaf(x0, cw0, acc);
    acc = fmaf(x1, cw1, acc);
    acc = fmaf(x2, cw2, acc);
    acc = fmaf(x3, cw3, acc);
    const float uv = acc / (1.f + __expf(-acc));
    const int off = (b * L_SZ + l) * D_SZ + gi;
    u[off] = uv;
    const float dtv = dt[off];
    Tdt[ty + 8 * r][tx] = dtv;
    Tdu[ty + 8 * r][tx] = dtv * uv;
  }
  __syncthreads();
#pragma unroll
  for (int r = 0; r < 4; ++r) {
    const int il = ty + 8 * r;
    const int off = (b * D_SZ + i0 + il) * L_SZ + l0 + tx;
    dt_t[off] = Tdt[tx][il];
    dtu_t[off] = Tdu[tx][il];
  }
}

// ---------------------------------------------------------------------------
// Selective scan v24 = v23 (R13-proven: SMEM dt/dtu + packed Cm via plain
// C loads) with the Cm software pipeline deepened 1 -> 2 chunks. R13's
// residual: scan 43us = ~30us VALU floor + ~13us stall; 1-deep prefetch
// (issue-to-use ~1 compute phase ~300cyc) only marginally covers L2-hit
// latency (~200-300cyc). 2-deep doubles the cover. Straight-line 6-STEP
// body lets the compiler rename the rotating register pairs (no v_movs
// except across the loop back-edge). VGPR 12 -> ~16 (no occupancy change).
// ---------------------------------------------------------------------------
struct SChunk {
  f32x4 d0, d1, u0, u1;  // dt[0..7], dtu[0..7] in SGPRs
};

#define SLOAD_CHUNK(S, SDT, SDU)                                               \
  asm volatile("s_load_dwordx4 %0, %4, 0x0\n\t"                                \
               "s_load_dwordx4 %1, %4, 0x10\n\t"                               \
               "s_load_dwordx4 %2, %5, 0x0\n\t"                                \
               "s_load_dwordx4 %3, %5, 0x10"                                   \
               : "=&s"(S.d0), "=&s"(S.d1), "=&s"(S.u0), "=&s"(S.u1)            \
               : "s"(SDT), "s"(SDU));

#define SWAIT(S)                                                               \
  asm volatile("s_waitcnt lgkmcnt(0)"                                          \
               : "+s"(S.d0), "+s"(S.d1), "+s"(S.u0), "+s"(S.u1))

#define SADV()                                                                 \
  { sdt += 8; sdu += 8; }

__global__ __launch_bounds__(64, 4) void scan_kernel(
    const float* __restrict__ A_log, const float* __restrict__ dt_t,
    const float* __restrict__ dtu_t, const float* __restrict__ Bm,
    const u32x2* __restrict__ Cmq, float* __restrict__ part) {
  // XCD-aware remap (v12-proven): xcd = bid&7 owns contiguous sids.
  const int bid = blockIdx.x;        // 0..4607
  const int xcd = bid & 7;
  const int slot = bid >> 3;         // 0..575 within this XCD
  const int sid = xcd * 96 + slot / 6;
  const int w = slot % 6;            // j-split
  const int lane = threadIdx.x;      // 0..63
  const int b = sid / D_SZ;
  const int i = sid % D_SZ;
  const int j = w * 64 + lane;

  const float a2 = -__expf(A_log[i * S_SZ + j]) * LOG2E;
  const float bw = Bm[(b * D_SZ + i) * S_SZ + j];
  float h = 0.f;

  const float* sdt = dt_t + (b * D_SZ + i) * L_SZ;   // uniform -> SMEM
  const float* sdu = dtu_t + (b * D_SZ + i) * L_SZ;  // uniform -> SMEM
  // Packed Cm: u32x2 index (b*96 + l/4)*384 + j. Chunk c = groups 2c,2c+1:
  // qa at cq[0], qb at cq[384]; advance 768 per chunk.
  const u32x2* cq = Cmq + (b * 96) * 384 + j;

  // fold result mapping: lane r holds value s = (b3<<2)|(b2<<1)|b0 of chunk;
  // lanes with bits {1,4,5} == 0 store (8 lanes cover s=0..7).
  const int sq = (((lane >> 3) & 1) << 2) | (((lane >> 2) & 1) << 1) | (lane & 1);
  const bool storer = (lane & 0x32) == 0;
  float* pstore = part + ((w * B_SZ + b) * D_SZ + i) * L_SZ + sq;

  auto compute_chunk = [&](u32x2 qa_c, u32x2 qb_c, SChunk& S) {
    float acc[8];
    const float dts[8] = {S.d0[0], S.d0[1], S.d0[2], S.d0[3],
                          S.d1[0], S.d1[1], S.d1[2], S.d1[3]};
    const float dus[8] = {S.u0[0], S.u0[1], S.u0[2], S.u0[3],
                          S.u1[0], S.u1[1], S.u1[2], S.u1[3]};
    const unsigned int qs[4] = {qa_c[0], qa_c[1], qb_c[0], qb_c[1]};
#pragma unroll
    for (int s = 0; s < 8; ++s) {
      const float e = fexp2(dts[s] * a2);
      h = fmaf(e, h, bw * dus[s]);
      // bf16 pair unpack: even l = low half <<16, odd l = high half masked
      const unsigned int cw32 =
          (s & 1) ? (qs[s >> 1] & 0xFFFF0000u) : (qs[s >> 1] << 16);
      acc[s] = h * __uint_as_float(cw32);
    }
    // fold stage 1: pairing xor15 (row_mirror), side bit3, n2=4
    {
      const bool hi = (lane & 8) != 0;
#pragma unroll
      for (int q = 0; q < 4; ++q) {
        const float keep = hi ? acc[q + 4] : acc[q];
        const float send = hi ? acc[q] : acc[q + 4];
        acc[q] = keep + dpp_mov<0x140>(send);
      }
    }
    // fold stage 2: pairing xor7 (row_half_mirror), side bit2, n2=2
    {
      const bool hi = (lane & 4) != 0;
#pragma unroll
      for (int q = 0; q < 2; ++q) {
        const float keep = hi ? acc[q + 2] : acc[q];
        const float send = hi ? acc[q] : acc[q + 2];
        acc[q] = keep + dpp_mov<0x141>(send);
      }
    }
    // fold stage 3: pairing xor1 (quad_perm [1,0,3,2]), side bit0, n2=1
    {
      const bool hi = (lane & 1) != 0;
      const float keep = hi ? acc[1] : acc[0];
      const float send = hi ? acc[0] : acc[1];
      acc[0] = keep + dpp_mov<0xB1>(send);
    }
    // finish across unused bits {1,4,5}: all VALU-pipe lane exchanges
    float r = acc[0];
    r += dpp_mov<0x4E>(r);   // xor2: quad_perm [2,3,0,1]
    r = fold_xor16(r);       // xor16: permlane16_swap builtin
    r = fold_xor32(r);       // xor32: permlane32_swap builtin
    if (storer) *pstore = r;
    pstore += 8;
  };

  SChunk S0, S1;
  // 2-deep Cm pipeline: chunk 0 and 1 in flight before the first compute.
  u32x2 qa0 = cq[0], qb0 = cq[384];  cq += 768;   // chunk 0
  u32x2 qa1 = cq[0], qb1 = cq[384];  cq += 768;   // chunk 1
  SLOAD_CHUNK(S0, sdt, sdu); SADV(); // chunk 0 (SMEM)

  // STEP(c): issue chunk c+2's Cm loads; drain+reissue SMEM; compute
  // chunk c; rotate the 2-deep pipeline.
#define STEP(SC, SN)                                                           \
  {                                                                            \
    const u32x2 qa_n = cq[0];                                                  \
    const u32x2 qb_n = cq[384];                                                \
    cq += 768;                                                                 \
    SWAIT(SC);                                                                 \
    SLOAD_CHUNK(SN, sdt, sdu);                                                 \
    SADV();                                                                    \
    compute_chunk(qa0, qb0, SC);                                               \
    qa0 = qa1; qb0 = qb1;                                                      \
    qa1 = qa_n; qb1 = qb_n;                                                    \
  }

#pragma unroll 1
  for (int it = 0; it < 8; ++it) {   // 6 chunks/iter: S alternation closes
    STEP(S0, S1);
    STEP(S1, S0);
    STEP(S0, S1);
    STEP(S1, S0);
    STEP(S0, S1);
    STEP(S1, S0);
  }
#undef STEP
  // 48 chunks computed. Final prefetches (chunks 48,49) are dead loads
  // (DCE-able); if emitted they read at/just past Cmq's end into xdblbf
  // (same workspace, valid memory). The dangling SMEM prefetch writes
  // dead SGPRs. Kernel ends here — no code after the loop (v16 lesson).
}

// ---------------------------------------------------------------------------
// Combine + transpose: y[b,l,i] = sum_{w<6} part[w][b][i][l] + u[b,l,i]*D[i]
// ---------------------------------------------------------------------------
__global__ __launch_bounds__(256) void combine_kernel(
    const float* __restrict__ part, const float* __restrict__ u,
    const float* __restrict__ Dv, float* __restrict__ y) {
  __shared__ float T[32][33];
  const int tx = threadIdx.x;
  const int ty0 = threadIdx.y;
  const int b = blockIdx.z;
  const int i0 = blockIdx.y * 32;
  const int l0 = blockIdx.x * 32;
#pragma unroll
  for (int r = 0; r < 4; ++r) {
    const int il = ty0 + 8 * r;
    float s = 0.f;
#pragma unroll
    for (int w = 0; w < 6; ++w)
      s += part[((w * B_SZ + b) * D_SZ + i0 + il) * L_SZ + l0 + tx];
    T[il][tx] = s;
  }
  __syncthreads();
#pragma unroll
  for (int r = 0; r < 4; ++r) {
    const int ll = ty0 + 8 * r;
    const int gi = i0 + tx;
    const int off = (b * L_SZ + l0 + ll) * D_SZ + gi;
    y[off] = fmaf(u[off], Dv[gi], T[tx][ll]);
  }
}

extern "C" void kernel_launch(void* const* d_in, const int* in_sizes, int n_in,
                              void* d_out, int out_size, void* d_ws,
                              size_t ws_size, hipStream_t stream) {
  const float* x = (const float*)d_in[0];
  const float* A_log = (const float*)d_in[1];
  const float* D = (const float*)d_in[2];
  const float* dt_w = (const float*)d_in[3];
  const float* dt_b = (const float*)d_in[4];
  const float* B_w = (const float*)d_in[5];
  const float* C_w = (const float*)d_in[6];
  const float* conv_w = (const float*)d_in[7];
  const float* conv_b = (const float*)d_in[8];
  float* y = (float*)d_out;

  float* ws = (float*)d_ws;
  float* dt = ws;                     // slot 0  [b,l,i]
  float* u = ws + TOT_ELEMS;          // slot 1
  float* Bm = ws + 2 * TOT_ELEMS;     // slot 2
  float* dt_t = ws + 3 * TOT_ELEMS;   // slot 3  [b,i,l]
  float* dtu_t = ws + 4 * TOT_ELEMS;  // slot 4  [b,i,l]
  float* part = ws + 5 * TOT_ELEMS;   // slots 5..10  [w][b][i][l], w<6
  unsigned short* bfarea = (unsigned short*)(ws + 11 * TOT_ELEMS);
  u32x2* Cmq = (u32x2*)bfarea;                 // 589824 B (packed bf16 Cm)
  unsigned short* xdblbf = bfarea + TOT_ELEMS; // 589824 B

  mfma_dual_gemm<1><<<dim3(24, 24), 128, 0, stream>>>(x, dt_w, B_w, dt_b, dt, xdblbf);
  mfma_dual_gemm<2><<<dim3(24, 24), 128, 0, stream>>>(xdblbf, B_w, C_w, nullptr, Bm, Cmq);
  conv_tr_kernel<<<dim3(L_SZ / 32, D_SZ / 32, B_SZ), dim3(32, 8), 0, stream>>>(
      x, conv_w, conv_b, dt, u, dt_t, dtu_t);
  scan_kernel<<<4608, 64, 0, stream>>>(A_log, dt_t, dtu_t, Bm, Cmq, part);
  combine_kernel<<<dim3(L_SZ / 32, D_SZ / 32, B_SZ), dim3(32, 8), 0, stream>>>(
      part, u, D, y);
}

// Round 15
// 128.124 us; speedup vs baseline: 1.0129x; 1.0129x over previous
//
#include <hip/hip_runtime.h>
#include <math.h>

// Dims (fixed by the problem)
#define B_SZ 2
#define L_SZ 384
#define D_SZ 384
#define S_SZ 384
#define BLK_ELEMS (L_SZ * D_SZ)        // 147456 per batch
#define TOT_ELEMS (B_SZ * L_SZ * D_SZ) // 294912
#define LOG2E 1.4426950408889634f

typedef __attribute__((ext_vector_type(8))) short bf16x8;
typedef __attribute__((ext_vector_type(4))) float f32x4;
typedef __attribute__((ext_vector_type(2))) unsigned int u32x2;

__device__ __forceinline__ float fexp2(float x) {
  return __builtin_amdgcn_exp2f(x);
}
__device__ __forceinline__ float softplus_f(float z) {
  return (z > 20.f) ? z : log1pf(__expf(z));
}
__device__ __forceinline__ unsigned short f2bf(float f) {  // RNE f32->bf16
  unsigned int u = __float_as_uint(f);
  return (unsigned short)((u + 0x7FFFu + ((u >> 16) & 1u)) >> 16);
}
#define PIPELINE_FENCE() asm volatile("" ::: "memory")

// 8x f32 -> 8x bf16 (RNE) via v_cvt_pk_bf16_f32. SAFE here: inputs come
// from memory loads (counter-based waitcnts cover asm operands). NOT safe
// for MFMA results — the MFMA-dst->VALU-read wait-state hazard is
// invisible through inline asm (v20-22 NaN lesson).
__device__ __forceinline__ bf16x8 cvt8(const float* p) {
  const f32x4 v0 = *(const f32x4*)p;
  const f32x4 v1 = *(const f32x4*)(p + 4);
  union { unsigned int u[4]; bf16x8 v; } r;
  asm("v_cvt_pk_bf16_f32 %0, %1, %2" : "=v"(r.u[0]) : "v"(v0[0]), "v"(v0[1]));
  asm("v_cvt_pk_bf16_f32 %0, %1, %2" : "=v"(r.u[1]) : "v"(v0[2]), "v"(v0[3]));
  asm("v_cvt_pk_bf16_f32 %0, %1, %2" : "=v"(r.u[2]) : "v"(v1[0]), "v"(v1[1]));
  asm("v_cvt_pk_bf16_f32 %0, %1, %2" : "=v"(r.u[3]) : "v"(v1[2]), "v"(v1[3]));
  return r.v;
}

// DPP lane exchange (VALU pipe). CTRL: 0x140=row_mirror (xor15),
// 0x141=row_half_mirror (xor7), 0xB1=quad_perm[1,0,3,2] (xor1),
// 0x4E=quad_perm[2,3,0,1] (xor2).
template <int CTRL>
__device__ __forceinline__ float dpp_mov(float v) {
  return __int_as_float(
      __builtin_amdgcn_update_dpp(0, __float_as_int(v), CTRL, 0xF, 0xF, true));
}

// r + shfl_xor(r,16)/(r,32) in ALL lanes via permlane*_swap BUILTINS
// (raw asm hit the gfx950 VALU-write->permlane wait-state hazard, v13).
__device__ __forceinline__ float fold_xor16(float r) {
#if __has_builtin(__builtin_amdgcn_permlane16_swap)
  const unsigned ru = __float_as_uint(r);
  u32x2 p = __builtin_amdgcn_permlane16_swap(ru, ru, false, false);
  return __uint_as_float(p[0]) + __uint_as_float(p[1]);
#else
  return r + __shfl_xor(r, 16, 64);
#endif
}
__device__ __forceinline__ float fold_xor32(float r) {
#if __has_builtin(__builtin_amdgcn_permlane32_swap)
  const unsigned ru = __float_as_uint(r);
  u32x2 p = __builtin_amdgcn_permlane32_swap(ru, ru, false, false);
  return __uint_as_float(p[0]) + __uint_as_float(p[1]);
#else
  return r + __shfl_xor(r, 32, 64);
#endif
}

// ---------------------------------------------------------------------------
// MERGED GEMM1 + conv + transpose (v25). Rationale: total - scan has been
// pinned at 84-85us across R2-R14 while scan dropped 55->43; kernel-count
// deltas (R7: -1 kernel = -6.3us non-scan) show each small kernel costs
// ~5-7us launch+work. The conv tile (32l x 32i) == one GEMM1 block's output
// if blocks compute 32x32 (grid 12 x 24, two 16-col tiles). Phases:
//   1. stage x/dt_w/B_w tiles to LDS (bf16, cvt8-from-loads: safe asm)
//   2. dual MFMA, 2 col-tiles each: acc1{a,b}=dt, acc2{a,b}=xdbl
//   3. barrier (all waves done reading sA/sW) -> xdbl stores; softplus in
//      PLAIN C (hazard-safe acc reads) -> Tdt LDS tile ALIASED over sA
//   4. barrier -> verbatim conv/silu/transpose code, dt from LDS (x re-read
//      from global f32 for precision; L2-hot). dt never touches global.
// Removes one kernel launch + dt's 2.4MB round-trip.
// ---------------------------------------------------------------------------
__global__ __launch_bounds__(128, 2) void gemm1_conv_kernel(
    const float* __restrict__ x, const float* __restrict__ dt_w,
    const float* __restrict__ B_w, const float* __restrict__ dt_b,
    const float* __restrict__ cw, const float* __restrict__ cb,
    unsigned short* __restrict__ xdbl, float* __restrict__ u,
    float* __restrict__ dt_t, float* __restrict__ dtu_t) {
  __shared__ unsigned short sA[32 * 392];   // x tile; later aliased Tdt/Tdu
  __shared__ unsigned short sW1[32 * 392];  // dt_w 32-col tile
  __shared__ unsigned short sW2[32 * 392];  // B_w 32-col tile
  float* const Tdt = (float*)sA;            // [32][33] f32
  float* const Tdu = (float*)sA + 32 * 33;  // [32][33] f32 (8448B <= 25088B)

  const int t = threadIdx.x;
  const int wv = t >> 6;
  const int lane = t & 63;
  const int ip = blockIdx.x;    // i col-pair tile: cols [ip*32, +32)
  const int mrow = blockIdx.y;  // 32 rows = (b = mrow/12, l0 = (mrow%12)*32)

  const float* Ab = x + mrow * 32 * 384;
  const float* W1b = dt_w + ip * 32 * 384;
  const float* W2b = B_w + ip * 32 * 384;
#pragma unroll
  for (int it = 0; it < 12; ++it) {
    const int id = t + it * 128;
    const int row = id / 48, col = id - row * 48;
    *(bf16x8*)&sA[row * 392 + col * 8] = cvt8(Ab + id * 8);
    *(bf16x8*)&sW1[row * 392 + col * 8] = cvt8(W1b + id * 8);
    *(bf16x8*)&sW2[row * 392 + col * 8] = cvt8(W2b + id * 8);
  }
  __syncthreads();

  const int rc = lane & 15;
  const int quad = lane >> 4;
  f32x4 acc1a = {0.f, 0.f, 0.f, 0.f}, acc1b = {0.f, 0.f, 0.f, 0.f};
  f32x4 acc2a = {0.f, 0.f, 0.f, 0.f}, acc2b = {0.f, 0.f, 0.f, 0.f};
#pragma unroll
  for (int kt = 0; kt < 12; ++kt) {
    const int ko = quad * 8 + kt * 32;
    const bf16x8 af = *(const bf16x8*)&sA[(wv * 16 + rc) * 392 + ko];
    const bf16x8 w1a = *(const bf16x8*)&sW1[rc * 392 + ko];
    const bf16x8 w1b = *(const bf16x8*)&sW1[(16 + rc) * 392 + ko];
    const bf16x8 w2a = *(const bf16x8*)&sW2[rc * 392 + ko];
    const bf16x8 w2b = *(const bf16x8*)&sW2[(16 + rc) * 392 + ko];
    acc1a = __builtin_amdgcn_mfma_f32_16x16x32_bf16(af, w1a, acc1a, 0, 0, 0);
    acc1b = __builtin_amdgcn_mfma_f32_16x16x32_bf16(af, w1b, acc1b, 0, 0, 0);
    acc2a = __builtin_amdgcn_mfma_f32_16x16x32_bf16(af, w2a, acc2a, 0, 0, 0);
    acc2b = __builtin_amdgcn_mfma_f32_16x16x32_bf16(af, w2b, acc2b, 0, 0, 0);
  }
  __syncthreads();  // all waves done reading sA/sW before Tdt aliasing

  // Epilogue: xdbl (bf16 global, row-major) + dt (softplus -> LDS tile).
  const int lrow0 = wv * 16 + quad * 4;       // l-local
  const int grow0 = mrow * 32 + lrow0;        // global row (b,l)
  const int gcola = ip * 32 + rc;             // global col (i)
  const int gcolb = gcola + 16;
  const float bba = dt_b[gcola];
  const float bbb = dt_b[gcolb];
#pragma unroll
  for (int r = 0; r < 4; ++r) {
    xdbl[(grow0 + r) * 384 + gcola] = f2bf(acc2a[r]);
    xdbl[(grow0 + r) * 384 + gcolb] = f2bf(acc2b[r]);
    Tdt[(lrow0 + r) * 33 + rc] = softplus_f(acc1a[r] + bba);
    Tdt[(lrow0 + r) * 33 + rc + 16] = softplus_f(acc1b[r] + bbb);
  }
  __syncthreads();

  // Conv + SiLU phase (verbatim conv_tr logic; dt from LDS, x from global).
  const int tx = t & 31;       // i-local
  const int tyc = t >> 5;      // 0..3
  const int b = mrow / 12;
  const int l0 = (mrow % 12) * 32;
  const int i0 = ip * 32;
  const int gi = i0 + tx;
  const float cbv = cb[gi];
  const float cw0 = cw[gi * 4 + 0], cw1 = cw[gi * 4 + 1];
  const float cw2 = cw[gi * 4 + 2], cw3 = cw[gi * 4 + 3];
#pragma unroll
  for (int r = 0; r < 8; ++r) {
    const int ll = tyc + 4 * r;          // l-local 0..31
    const int l = l0 + ll;               // per-batch l (guards vs 0)
    float acc = cbv;
    const float x3 = x[(b * L_SZ + l) * D_SZ + gi];
    const float x2 = (l >= 1) ? x[(b * L_SZ + l - 1) * D_SZ + gi] : 0.f;
    const float x1 = (l >= 2) ? x[(b * L_SZ + l - 2) * D_SZ + gi] : 0.f;
    const float x0 = (l >= 3) ? x[(b * L_SZ + l - 3) * D_SZ + gi] : 0.f;
    acc = fmaf(x0, cw0, acc);
    acc = fmaf(x1, cw1, acc);
    acc = fmaf(x2, cw2, acc);
    acc = fmaf(x3, cw3, acc);
    const float uv = acc / (1.f + __expf(-acc));
    u[(b * L_SZ + l) * D_SZ + gi] = uv;
    Tdu[ll * 33 + tx] = Tdt[ll * 33 + tx] * uv;
  }
  __syncthreads();
  // Transpose-out: dt_t/dtu_t [b,i,l] (tx plays l-local, il = i-local).
#pragma unroll
  for (int r = 0; r < 8; ++r) {
    const int il = tyc + 4 * r;
    const int off = (b * D_SZ + i0 + il) * L_SZ + l0 + tx;
    dt_t[off] = Tdt[tx * 33 + il];
    dtu_t[off] = Tdu[tx * 33 + il];
  }
}

// ---------------------------------------------------------------------------
// GEMM2 (old MODE2 path, standalone): A=xdbl bf16, O1=Bm f32, O2=Cm packed
// u32x2 per (l-group of 4, col) — plain-C f2bf pack (R13-proven hazard-safe).
// ---------------------------------------------------------------------------
__global__ __launch_bounds__(128, 2) void mfma_gemm2(
    const unsigned short* __restrict__ Abf, const float* __restrict__ W1,
    const float* __restrict__ W2, float* __restrict__ O1,
    u32x2* __restrict__ O2q) {
  __shared__ unsigned short sA[32 * 392];
  __shared__ unsigned short sW1[16 * 392];
  __shared__ unsigned short sW2[16 * 392];

  const int t = threadIdx.x;
  const int wv = t >> 6;
  const int lane = t & 63;
  const int nt = blockIdx.x;
  const int mrow = blockIdx.y;

  const unsigned short* Ab = Abf + mrow * 32 * 384;
  const float* W1b = W1 + nt * 16 * 384;
  const float* W2b = W2 + nt * 16 * 384;

#pragma unroll
  for (int it = 0; it < 12; ++it) {
    const int id = t + it * 128;
    const int row = id / 48, col = id - row * 48;
    *(bf16x8*)&sA[row * 392 + col * 8] = *(const bf16x8*)(Ab + id * 8);
  }
#pragma unroll
  for (int it = 0; it < 6; ++it) {
    const int id = t + it * 128;
    const int row = id / 48, col = id - row * 48;
    *(bf16x8*)&sW1[row * 392 + col * 8] = cvt8(W1b + id * 8);
    *(bf16x8*)&sW2[row * 392 + col * 8] = cvt8(W2b + id * 8);
  }
  __syncthreads();

  const int rc = lane & 15;
  const int quad = lane >> 4;
  bf16x8 af[12], w1f[12], w2f[12];
#pragma unroll
  for (int kt = 0; kt < 12; ++kt) {
    af[kt] = *(const bf16x8*)&sA[(wv * 16 + rc) * 392 + quad * 8 + kt * 32];
    w1f[kt] = *(const bf16x8*)&sW1[rc * 392 + quad * 8 + kt * 32];
    w2f[kt] = *(const bf16x8*)&sW2[rc * 392 + quad * 8 + kt * 32];
  }
  PIPELINE_FENCE();
  f32x4 acc1 = {0.f, 0.f, 0.f, 0.f};
  f32x4 acc2 = {0.f, 0.f, 0.f, 0.f};
#pragma unroll
  for (int kt = 0; kt < 12; ++kt) {
    acc1 = __builtin_amdgcn_mfma_f32_16x16x32_bf16(af[kt], w1f[kt], acc1, 0, 0, 0);
    acc2 = __builtin_amdgcn_mfma_f32_16x16x32_bf16(af[kt], w2f[kt], acc2, 0, 0, 0);
  }
  const int col = nt * 16 + rc;
  const int row0 = mrow * 32 + wv * 16 + quad * 4;   // multiple of 4
#pragma unroll
  for (int r = 0; r < 4; ++r)
    O1[(row0 + r) * 384 + col] = acc1[r];
  const unsigned int p01 =
      (unsigned int)f2bf(acc2[0]) | ((unsigned int)f2bf(acc2[1]) << 16);
  const unsigned int p23 =
      (unsigned int)f2bf(acc2[2]) | ((unsigned int)f2bf(acc2[3]) << 16);
  u32x2 q = {p01, p23};
  O2q[(row0 >> 2) * 384 + col] = q;
}

// ---------------------------------------------------------------------------
// Selective scan v23 (R13-proven verbatim: SMEM dt/dtu + packed Cm via
// plain-C loads, 1-deep pipeline — R14's 2-deep was null, reverted).
// ---------------------------------------------------------------------------
struct SChunk {
  f32x4 d0, d1, u0, u1;  // dt[0..7], dtu[0..7] in SGPRs
};

#define SLOAD_CHUNK(S, SDT, SDU)                                               \
  asm volatile("s_load_dwordx4 %0, %4, 0x0\n\t"                                \
               "s_load_dwordx4 %1, %4, 0x10\n\t"                               \
               "s_load_dwordx4 %2, %5, 0x0\n\t"                                \
               "s_load_dwordx4 %3, %5, 0x10"                                   \
               : "=&s"(S.d0), "=&s"(S.d1), "=&s"(S.u0), "=&s"(S.u1)            \
               : "s"(SDT), "s"(SDU));

#define SWAIT(S)                                                               \
  asm volatile("s_waitcnt lgkmcnt(0)"                                          \
               : "+s"(S.d0), "+s"(S.d1), "+s"(S.u0), "+s"(S.u1))

#define SADV()                                                                 \
  { sdt += 8; sdu += 8; }

__global__ __launch_bounds__(64, 4) void scan_kernel(
    const float* __restrict__ A_log, const float* __restrict__ dt_t,
    const float* __restrict__ dtu_t, const float* __restrict__ Bm,
    const u32x2* __restrict__ Cmq, float* __restrict__ part) {
  // XCD-aware remap (v12-proven): xcd = bid&7 owns contiguous sids.
  const int bid = blockIdx.x;        // 0..4607
  const int xcd = bid & 7;
  const int slot = bid >> 3;         // 0..575 within this XCD
  const int sid = xcd * 96 + slot / 6;
  const int w = slot % 6;            // j-split
  const int lane = threadIdx.x;      // 0..63
  const int b = sid / D_SZ;
  const int i = sid % D_SZ;
  const int j = w * 64 + lane;

  const float a2 = -__expf(A_log[i * S_SZ + j]) * LOG2E;
  const float bw = Bm[(b * D_SZ + i) * S_SZ + j];
  float h = 0.f;

  const float* sdt = dt_t + (b * D_SZ + i) * L_SZ;   // uniform -> SMEM
  const float* sdu = dtu_t + (b * D_SZ + i) * L_SZ;  // uniform -> SMEM
  // Packed Cm: u32x2 index (b*96 + l/4)*384 + j. Chunk c = groups 2c,2c+1:
  // qa at cq[0], qb at cq[384]; advance 768 per chunk.
  const u32x2* cq = Cmq + (b * 96) * 384 + j;

  // fold result mapping: lane r holds value s = (b3<<2)|(b2<<1)|b0 of chunk;
  // lanes with bits {1,4,5} == 0 store (8 lanes cover s=0..7).
  const int sq = (((lane >> 3) & 1) << 2) | (((lane >> 2) & 1) << 1) | (lane & 1);
  const bool storer = (lane & 0x32) == 0;
  float* pstore = part + ((w * B_SZ + b) * D_SZ + i) * L_SZ + sq;

  auto compute_chunk = [&](u32x2 qa_c, u32x2 qb_c, SChunk& S) {
    float acc[8];
    const float dts[8] = {S.d0[0], S.d0[1], S.d0[2], S.d0[3],
                          S.d1[0], S.d1[1], S.d1[2], S.d1[3]};
    const float dus[8] = {S.u0[0], S.u0[1], S.u0[2], S.u0[3],
                          S.u1[0], S.u1[1], S.u1[2], S.u1[3]};
    const unsigned int qs[4] = {qa_c[0], qa_c[1], qb_c[0], qb_c[1]};
#pragma unroll
    for (int s = 0; s < 8; ++s) {
      const float e = fexp2(dts[s] * a2);
      h = fmaf(e, h, bw * dus[s]);
      // bf16 pair unpack: even l = low half <<16, odd l = high half masked
      const unsigned int cw32 =
          (s & 1) ? (qs[s >> 1] & 0xFFFF0000u) : (qs[s >> 1] << 16);
      acc[s] = h * __uint_as_float(cw32);
    }
    // fold stage 1: pairing xor15 (row_mirror), side bit3, n2=4
    {
      const bool hi = (lane & 8) != 0;
#pragma unroll
      for (int q = 0; q < 4; ++q) {
        const float keep = hi ? acc[q + 4] : acc[q];
        const float send = hi ? acc[q] : acc[q + 4];
        acc[q] = keep + dpp_mov<0x140>(send);
      }
    }
    // fold stage 2: pairing xor7 (row_half_mirror), side bit2, n2=2
    {
      const bool hi = (lane & 4) != 0;
#pragma unroll
      for (int q = 0; q < 2; ++q) {
        const float keep = hi ? acc[q + 2] : acc[q];
        const float send = hi ? acc[q] : acc[q + 2];
        acc[q] = keep + dpp_mov<0x141>(send);
      }
    }
    // fold stage 3: pairing xor1 (quad_perm [1,0,3,2]), side bit0, n2=1
    {
      const bool hi = (lane & 1) != 0;
      const float keep = hi ? acc[1] : acc[0];
      const float send = hi ? acc[0] : acc[1];
      acc[0] = keep + dpp_mov<0xB1>(send);
    }
    // finish across unused bits {1,4,5}: all VALU-pipe lane exchanges
    float r = acc[0];
    r += dpp_mov<0x4E>(r);   // xor2: quad_perm [2,3,0,1]
    r = fold_xor16(r);       // xor16: permlane16_swap builtin
    r = fold_xor32(r);       // xor32: permlane32_swap builtin
    if (storer) *pstore = r;
    pstore += 8;
  };

  SChunk S0, S1;
  u32x2 qa = cq[0], qb = cq[384];    // chunk 0 (compiler-managed loads)
  cq += 768;
  SLOAD_CHUNK(S0, sdt, sdu); SADV(); // chunk 0 (SMEM)

  // STEP(c): issue chunk c+1's Cm loads (compiler schedules them early and
  // inserts its own waitcnt at first use); drain+reissue SMEM; compute
  // chunk c; rotate.
#define STEP(SC, SN)                                                           \
  {                                                                            \
    const u32x2 qa_n = cq[0];                                                  \
    const u32x2 qb_n = cq[384];                                                \
    cq += 768;                                                                 \
    SWAIT(SC);                                                                 \
    SLOAD_CHUNK(SN, sdt, sdu);                                                 \
    SADV();                                                                    \
    compute_chunk(qa, qb, SC);                                                 \
    qa = qa_n;                                                                 \
    qb = qb_n;                                                                 \
  }

#pragma unroll 1
  for (int it = 0; it < 8; ++it) {   // 6 chunks/iter: S alternation closes
    STEP(S0, S1);
    STEP(S1, S0);
    STEP(S0, S1);
    STEP(S1, S0);
    STEP(S0, S1);
    STEP(S1, S0);
  }
#undef STEP
  // 48 chunks computed. The final prefetch loads are dead (DCE'd by the
  // compiler); the dangling SMEM prefetch writes dead SGPRs and reads
  // valid workspace. Kernel ends here — no code after the loop (v16).
}

// ---------------------------------------------------------------------------
// Combine + transpose: y[b,l,i] = sum_{w<6} part[w][b][i][l] + u[b,l,i]*D[i]
// ---------------------------------------------------------------------------
__global__ __launch_bounds__(256) void combine_kernel(
    const float* __restrict__ part, const float* __restrict__ u,
    const float* __restrict__ Dv, float* __restrict__ y) {
  __shared__ float T[32][33];
  const int tx = threadIdx.x;
  const int ty0 = threadIdx.y;
  const int b = blockIdx.z;
  const int i0 = blockIdx.y * 32;
  const int l0 = blockIdx.x * 32;
#pragma unroll
  for (int r = 0; r < 4; ++r) {
    const int il = ty0 + 8 * r;
    float s = 0.f;
#pragma unroll
    for (int w = 0; w < 6; ++w)
      s += part[((w * B_SZ + b) * D_SZ + i0 + il) * L_SZ + l0 + tx];
    T[il][tx] = s;
  }
  __syncthreads();
#pragma unroll
  for (int r = 0; r < 4; ++r) {
    const int ll = ty0 + 8 * r;
    const int gi = i0 + tx;
    const int off = (b * L_SZ + l0 + ll) * D_SZ + gi;
    y[off] = fmaf(u[off], Dv[gi], T[tx][ll]);
  }
}

extern "C" void kernel_launch(void* const* d_in, const int* in_sizes, int n_in,
                              void* d_out, int out_size, void* d_ws,
                              size_t ws_size, hipStream_t stream) {
  const float* x = (const float*)d_in[0];
  const float* A_log = (const float*)d_in[1];
  const float* D = (const float*)d_in[2];
  const float* dt_w = (const float*)d_in[3];
  const float* dt_b = (const float*)d_in[4];
  const float* B_w = (const float*)d_in[5];
  const float* C_w = (const float*)d_in[6];
  const float* conv_w = (const float*)d_in[7];
  const float* conv_b = (const float*)d_in[8];
  float* y = (float*)d_out;

  float* ws = (float*)d_ws;
  float* u = ws;                      // slot 0
  float* Bm = ws + TOT_ELEMS;         // slot 1
  float* dt_t = ws + 2 * TOT_ELEMS;   // slot 2  [b,i,l]
  float* dtu_t = ws + 3 * TOT_ELEMS;  // slot 3  [b,i,l]
  float* part = ws + 4 * TOT_ELEMS;   // slots 4..9  [w][b][i][l], w<6
  unsigned short* bfarea = (unsigned short*)(ws + 10 * TOT_ELEMS);
  u32x2* Cmq = (u32x2*)bfarea;                 // 589824 B (packed bf16 Cm)
  unsigned short* xdblbf = bfarea + TOT_ELEMS; // 589824 B (scan prefetch
                                               //  overreads spill here: safe)

  gemm1_conv_kernel<<<dim3(12, 24), 128, 0, stream>>>(
      x, dt_w, B_w, dt_b, conv_w, conv_b, xdblbf, u, dt_t, dtu_t);
  mfma_gemm2<<<dim3(24, 24), 128, 0, stream>>>(xdblbf, B_w, C_w, Bm, Cmq);
  scan_kernel<<<4608, 64, 0, stream>>>(A_log, dt_t, dtu_t, Bm, Cmq, part);
  combine_kernel<<<dim3(L_SZ / 32, D_SZ / 32, B_SZ), dim3(32, 8), 0, stream>>>(
      part, u, D, y);
}

// Round 16
// 127.937 us; speedup vs baseline: 1.0144x; 1.0015x over previous
//
#include <hip/hip_runtime.h>
#include <math.h>

// Dims (fixed by the problem)
#define B_SZ 2
#define L_SZ 384
#define D_SZ 384
#define S_SZ 384
#define BLK_ELEMS (L_SZ * D_SZ)        // 147456 per batch
#define TOT_ELEMS (B_SZ * L_SZ * D_SZ) // 294912
#define LOG2E 1.4426950408889634f

typedef __attribute__((ext_vector_type(8))) short bf16x8;
typedef __attribute__((ext_vector_type(4))) float f32x4;
typedef __attribute__((ext_vector_type(2))) unsigned int u32x2;

__device__ __forceinline__ float fexp2(float x) {
  return __builtin_amdgcn_exp2f(x);
}
__device__ __forceinline__ float softplus_f(float z) {
  return (z > 20.f) ? z : log1pf(__expf(z));
}
__device__ __forceinline__ unsigned short f2bf(float f) {  // RNE f32->bf16
  unsigned int u = __float_as_uint(f);
  return (unsigned short)((u + 0x7FFFu + ((u >> 16) & 1u)) >> 16);
}
#define PIPELINE_FENCE() asm volatile("" ::: "memory")

// 8x f32 -> 8x bf16 (RNE) via v_cvt_pk_bf16_f32. SAFE here: inputs come
// from memory loads (counter-based waitcnts cover asm operands). NOT safe
// for MFMA results — the MFMA-dst->VALU-read wait-state hazard is
// invisible through inline asm (v20-22 NaN lesson).
__device__ __forceinline__ bf16x8 cvt8(const float* p) {
  const f32x4 v0 = *(const f32x4*)p;
  const f32x4 v1 = *(const f32x4*)(p + 4);
  union { unsigned int u[4]; bf16x8 v; } r;
  asm("v_cvt_pk_bf16_f32 %0, %1, %2" : "=v"(r.u[0]) : "v"(v0[0]), "v"(v0[1]));
  asm("v_cvt_pk_bf16_f32 %0, %1, %2" : "=v"(r.u[1]) : "v"(v0[2]), "v"(v0[3]));
  asm("v_cvt_pk_bf16_f32 %0, %1, %2" : "=v"(r.u[2]) : "v"(v1[0]), "v"(v1[1]));
  asm("v_cvt_pk_bf16_f32 %0, %1, %2" : "=v"(r.u[3]) : "v"(v1[2]), "v"(v1[3]));
  return r.v;
}

// DPP lane exchange (VALU pipe). CTRL: 0x140=row_mirror (xor15),
// 0x141=row_half_mirror (xor7), 0xB1=quad_perm[1,0,3,2] (xor1),
// 0x4E=quad_perm[2,3,0,1] (xor2).
template <int CTRL>
__device__ __forceinline__ float dpp_mov(float v) {
  return __int_as_float(
      __builtin_amdgcn_update_dpp(0, __float_as_int(v), CTRL, 0xF, 0xF, true));
}

// r + shfl_xor(r,16)/(r,32) in ALL lanes via permlane*_swap BUILTINS
// (raw asm hit the gfx950 VALU-write->permlane wait-state hazard, v13).
__device__ __forceinline__ float fold_xor16(float r) {
#if __has_builtin(__builtin_amdgcn_permlane16_swap)
  const unsigned ru = __float_as_uint(r);
  u32x2 p = __builtin_amdgcn_permlane16_swap(ru, ru, false, false);
  return __uint_as_float(p[0]) + __uint_as_float(p[1]);
#else
  return r + __shfl_xor(r, 16, 64);
#endif
}
__device__ __forceinline__ float fold_xor32(float r) {
#if __has_builtin(__builtin_amdgcn_permlane32_swap)
  const unsigned ru = __float_as_uint(r);
  u32x2 p = __builtin_amdgcn_permlane32_swap(ru, ru, false, false);
  return __uint_as_float(p[0]) + __uint_as_float(p[1]);
#else
  return r + __shfl_xor(r, 32, 64);
#endif
}

// ---------------------------------------------------------------------------
// MERGED GEMM1 + conv + transpose (R15 version, kept: neutral vs split but
// one fewer kernel). Phases: stage -> dual MFMA (2 col-tiles each) ->
// barrier -> xdbl stores + softplus(acc1) into LDS (aliased over sA) ->
// barrier -> conv/silu/transpose with dt from LDS.
// ---------------------------------------------------------------------------
__global__ __launch_bounds__(128, 2) void gemm1_conv_kernel(
    const float* __restrict__ x, const float* __restrict__ dt_w,
    const float* __restrict__ B_w, const float* __restrict__ dt_b,
    const float* __restrict__ cw, const float* __restrict__ cb,
    unsigned short* __restrict__ xdbl, float* __restrict__ u,
    float* __restrict__ dt_t, float* __restrict__ dtu_t) {
  __shared__ unsigned short sA[32 * 392];   // x tile; later aliased Tdt/Tdu
  __shared__ unsigned short sW1[32 * 392];  // dt_w 32-col tile
  __shared__ unsigned short sW2[32 * 392];  // B_w 32-col tile
  float* const Tdt = (float*)sA;            // [32][33] f32
  float* const Tdu = (float*)sA + 32 * 33;  // [32][33] f32 (8448B <= 25088B)

  const int t = threadIdx.x;
  const int wv = t >> 6;
  const int lane = t & 63;
  const int ip = blockIdx.x;    // i col-pair tile: cols [ip*32, +32)
  const int mrow = blockIdx.y;  // 32 rows = (b = mrow/12, l0 = (mrow%12)*32)

  const float* Ab = x + mrow * 32 * 384;
  const float* W1b = dt_w + ip * 32 * 384;
  const float* W2b = B_w + ip * 32 * 384;
#pragma unroll
  for (int it = 0; it < 12; ++it) {
    const int id = t + it * 128;
    const int row = id / 48, col = id - row * 48;
    *(bf16x8*)&sA[row * 392 + col * 8] = cvt8(Ab + id * 8);
    *(bf16x8*)&sW1[row * 392 + col * 8] = cvt8(W1b + id * 8);
    *(bf16x8*)&sW2[row * 392 + col * 8] = cvt8(W2b + id * 8);
  }
  __syncthreads();

  const int rc = lane & 15;
  const int quad = lane >> 4;
  f32x4 acc1a = {0.f, 0.f, 0.f, 0.f}, acc1b = {0.f, 0.f, 0.f, 0.f};
  f32x4 acc2a = {0.f, 0.f, 0.f, 0.f}, acc2b = {0.f, 0.f, 0.f, 0.f};
#pragma unroll
  for (int kt = 0; kt < 12; ++kt) {
    const int ko = quad * 8 + kt * 32;
    const bf16x8 af = *(const bf16x8*)&sA[(wv * 16 + rc) * 392 + ko];
    const bf16x8 w1a = *(const bf16x8*)&sW1[rc * 392 + ko];
    const bf16x8 w1b = *(const bf16x8*)&sW1[(16 + rc) * 392 + ko];
    const bf16x8 w2a = *(const bf16x8*)&sW2[rc * 392 + ko];
    const bf16x8 w2b = *(const bf16x8*)&sW2[(16 + rc) * 392 + ko];
    acc1a = __builtin_amdgcn_mfma_f32_16x16x32_bf16(af, w1a, acc1a, 0, 0, 0);
    acc1b = __builtin_amdgcn_mfma_f32_16x16x32_bf16(af, w1b, acc1b, 0, 0, 0);
    acc2a = __builtin_amdgcn_mfma_f32_16x16x32_bf16(af, w2a, acc2a, 0, 0, 0);
    acc2b = __builtin_amdgcn_mfma_f32_16x16x32_bf16(af, w2b, acc2b, 0, 0, 0);
  }
  __syncthreads();  // all waves done reading sA/sW before Tdt aliasing

  // Epilogue: xdbl (bf16 global, row-major) + dt (softplus -> LDS tile).
  const int lrow0 = wv * 16 + quad * 4;       // l-local
  const int grow0 = mrow * 32 + lrow0;        // global row (b,l)
  const int gcola = ip * 32 + rc;             // global col (i)
  const int gcolb = gcola + 16;
  const float bba = dt_b[gcola];
  const float bbb = dt_b[gcolb];
#pragma unroll
  for (int r = 0; r < 4; ++r) {
    xdbl[(grow0 + r) * 384 + gcola] = f2bf(acc2a[r]);
    xdbl[(grow0 + r) * 384 + gcolb] = f2bf(acc2b[r]);
    Tdt[(lrow0 + r) * 33 + rc] = softplus_f(acc1a[r] + bba);
    Tdt[(lrow0 + r) * 33 + rc + 16] = softplus_f(acc1b[r] + bbb);
  }
  __syncthreads();

  // Conv + SiLU phase (dt from LDS, x from global).
  const int tx = t & 31;       // i-local
  const int tyc = t >> 5;      // 0..3
  const int b = mrow / 12;
  const int l0 = (mrow % 12) * 32;
  const int i0 = ip * 32;
  const int gi = i0 + tx;
  const float cbv = cb[gi];
  const float cw0 = cw[gi * 4 + 0], cw1 = cw[gi * 4 + 1];
  const float cw2 = cw[gi * 4 + 2], cw3 = cw[gi * 4 + 3];
#pragma unroll
  for (int r = 0; r < 8; ++r) {
    const int ll = tyc + 4 * r;          // l-local 0..31
    const int l = l0 + ll;               // per-batch l (guards vs 0)
    float acc = cbv;
    const float x3 = x[(b * L_SZ + l) * D_SZ + gi];
    const float x2 = (l >= 1) ? x[(b * L_SZ + l - 1) * D_SZ + gi] : 0.f;
    const float x1 = (l >= 2) ? x[(b * L_SZ + l - 2) * D_SZ + gi] : 0.f;
    const float x0 = (l >= 3) ? x[(b * L_SZ + l - 3) * D_SZ + gi] : 0.f;
    acc = fmaf(x0, cw0, acc);
    acc = fmaf(x1, cw1, acc);
    acc = fmaf(x2, cw2, acc);
    acc = fmaf(x3, cw3, acc);
    const float uv = acc / (1.f + __expf(-acc));
    u[(b * L_SZ + l) * D_SZ + gi] = uv;
    Tdu[ll * 33 + tx] = Tdt[ll * 33 + tx] * uv;
  }
  __syncthreads();
  // Transpose-out: dt_t/dtu_t [b,i,l] (tx plays l-local, il = i-local).
#pragma unroll
  for (int r = 0; r < 8; ++r) {
    const int il = tyc + 4 * r;
    const int off = (b * D_SZ + i0 + il) * L_SZ + l0 + tx;
    dt_t[off] = Tdt[tx * 33 + il];
    dtu_t[off] = Tdu[tx * 33 + il];
  }
}

// ---------------------------------------------------------------------------
// GEMM2: A=xdbl bf16, O1=Bm f32, O2=Cm packed u32x2 per (l-group, col) —
// plain-C f2bf pack (R13-proven hazard-safe).
// ---------------------------------------------------------------------------
__global__ __launch_bounds__(128, 2) void mfma_gemm2(
    const unsigned short* __restrict__ Abf, const float* __restrict__ W1,
    const float* __restrict__ W2, float* __restrict__ O1,
    u32x2* __restrict__ O2q) {
  __shared__ unsigned short sA[32 * 392];
  __shared__ unsigned short sW1[16 * 392];
  __shared__ unsigned short sW2[16 * 392];

  const int t = threadIdx.x;
  const int wv = t >> 6;
  const int lane = t & 63;
  const int nt = blockIdx.x;
  const int mrow = blockIdx.y;

  const unsigned short* Ab = Abf + mrow * 32 * 384;
  const float* W1b = W1 + nt * 16 * 384;
  const float* W2b = W2 + nt * 16 * 384;

#pragma unroll
  for (int it = 0; it < 12; ++it) {
    const int id = t + it * 128;
    const int row = id / 48, col = id - row * 48;
    *(bf16x8*)&sA[row * 392 + col * 8] = *(const bf16x8*)(Ab + id * 8);
  }
#pragma unroll
  for (int it = 0; it < 6; ++it) {
    const int id = t + it * 128;
    const int row = id / 48, col = id - row * 48;
    *(bf16x8*)&sW1[row * 392 + col * 8] = cvt8(W1b + id * 8);
    *(bf16x8*)&sW2[row * 392 + col * 8] = cvt8(W2b + id * 8);
  }
  __syncthreads();

  const int rc = lane & 15;
  const int quad = lane >> 4;
  bf16x8 af[12], w1f[12], w2f[12];
#pragma unroll
  for (int kt = 0; kt < 12; ++kt) {
    af[kt] = *(const bf16x8*)&sA[(wv * 16 + rc) * 392 + quad * 8 + kt * 32];
    w1f[kt] = *(const bf16x8*)&sW1[rc * 392 + quad * 8 + kt * 32];
    w2f[kt] = *(const bf16x8*)&sW2[rc * 392 + quad * 8 + kt * 32];
  }
  PIPELINE_FENCE();
  f32x4 acc1 = {0.f, 0.f, 0.f, 0.f};
  f32x4 acc2 = {0.f, 0.f, 0.f, 0.f};
#pragma unroll
  for (int kt = 0; kt < 12; ++kt) {
    acc1 = __builtin_amdgcn_mfma_f32_16x16x32_bf16(af[kt], w1f[kt], acc1, 0, 0, 0);
    acc2 = __builtin_amdgcn_mfma_f32_16x16x32_bf16(af[kt], w2f[kt], acc2, 0, 0, 0);
  }
  const int col = nt * 16 + rc;
  const int row0 = mrow * 32 + wv * 16 + quad * 4;   // multiple of 4
#pragma unroll
  for (int r = 0; r < 4; ++r)
    O1[(row0 + r) * 384 + col] = acc1[r];
  const unsigned int p01 =
      (unsigned int)f2bf(acc2[0]) | ((unsigned int)f2bf(acc2[1]) << 16);
  const unsigned int p23 =
      (unsigned int)f2bf(acc2[2]) | ((unsigned int)f2bf(acc2[3]) << 16);
  u32x2 q = {p01, p23};
  O2q[(row0 >> 2) * 384 + col] = q;
}

// ---------------------------------------------------------------------------
// Selective scan v26 = v23 (R13-proven) with ONE change: part stored as
// bf16 (f2bf in plain C). part was the last full-f32 intermediate —
// WRITE_SIZE 6.9MB (the scan's entire write traffic) + combine's re-read.
// Halves both. Precision: partials are O(1) summands; bf16 rel-err 0.4% x6
// adds <=0.2 vs threshold 6.72 (current absmax 1.25).
// ---------------------------------------------------------------------------
struct SChunk {
  f32x4 d0, d1, u0, u1;  // dt[0..7], dtu[0..7] in SGPRs
};

#define SLOAD_CHUNK(S, SDT, SDU)                                               \
  asm volatile("s_load_dwordx4 %0, %4, 0x0\n\t"                                \
               "s_load_dwordx4 %1, %4, 0x10\n\t"                               \
               "s_load_dwordx4 %2, %5, 0x0\n\t"                                \
               "s_load_dwordx4 %3, %5, 0x10"                                   \
               : "=&s"(S.d0), "=&s"(S.d1), "=&s"(S.u0), "=&s"(S.u1)            \
               : "s"(SDT), "s"(SDU));

#define SWAIT(S)                                                               \
  asm volatile("s_waitcnt lgkmcnt(0)"                                          \
               : "+s"(S.d0), "+s"(S.d1), "+s"(S.u0), "+s"(S.u1))

#define SADV()                                                                 \
  { sdt += 8; sdu += 8; }

__global__ __launch_bounds__(64, 4) void scan_kernel(
    const float* __restrict__ A_log, const float* __restrict__ dt_t,
    const float* __restrict__ dtu_t, const float* __restrict__ Bm,
    const u32x2* __restrict__ Cmq, unsigned short* __restrict__ part) {
  // XCD-aware remap (v12-proven): xcd = bid&7 owns contiguous sids.
  const int bid = blockIdx.x;        // 0..4607
  const int xcd = bid & 7;
  const int slot = bid >> 3;         // 0..575 within this XCD
  const int sid = xcd * 96 + slot / 6;
  const int w = slot % 6;            // j-split
  const int lane = threadIdx.x;      // 0..63
  const int b = sid / D_SZ;
  const int i = sid % D_SZ;
  const int j = w * 64 + lane;

  const float a2 = -__expf(A_log[i * S_SZ + j]) * LOG2E;
  const float bw = Bm[(b * D_SZ + i) * S_SZ + j];
  float h = 0.f;

  const float* sdt = dt_t + (b * D_SZ + i) * L_SZ;   // uniform -> SMEM
  const float* sdu = dtu_t + (b * D_SZ + i) * L_SZ;  // uniform -> SMEM
  // Packed Cm: u32x2 index (b*96 + l/4)*384 + j. Chunk c = groups 2c,2c+1:
  // qa at cq[0], qb at cq[384]; advance 768 per chunk.
  const u32x2* cq = Cmq + (b * 96) * 384 + j;

  // fold result mapping: lane r holds value s = (b3<<2)|(b2<<1)|b0 of chunk;
  // lanes with bits {1,4,5} == 0 store (8 lanes cover s=0..7).
  const int sq = (((lane >> 3) & 1) << 2) | (((lane >> 2) & 1) << 1) | (lane & 1);
  const bool storer = (lane & 0x32) == 0;
  unsigned short* pstore = part + ((w * B_SZ + b) * D_SZ + i) * L_SZ + sq;

  auto compute_chunk = [&](u32x2 qa_c, u32x2 qb_c, SChunk& S) {
    float acc[8];
    const float dts[8] = {S.d0[0], S.d0[1], S.d0[2], S.d0[3],
                          S.d1[0], S.d1[1], S.d1[2], S.d1[3]};
    const float dus[8] = {S.u0[0], S.u0[1], S.u0[2], S.u0[3],
                          S.u1[0], S.u1[1], S.u1[2], S.u1[3]};
    const unsigned int qs[4] = {qa_c[0], qa_c[1], qb_c[0], qb_c[1]};
#pragma unroll
    for (int s = 0; s < 8; ++s) {
      const float e = fexp2(dts[s] * a2);
      h = fmaf(e, h, bw * dus[s]);
      // bf16 pair unpack: even l = low half <<16, odd l = high half masked
      const unsigned int cw32 =
          (s & 1) ? (qs[s >> 1] & 0xFFFF0000u) : (qs[s >> 1] << 16);
      acc[s] = h * __uint_as_float(cw32);
    }
    // fold stage 1: pairing xor15 (row_mirror), side bit3, n2=4
    {
      const bool hi = (lane & 8) != 0;
#pragma unroll
      for (int q = 0; q < 4; ++q) {
        const float keep = hi ? acc[q + 4] : acc[q];
        const float send = hi ? acc[q] : acc[q + 4];
        acc[q] = keep + dpp_mov<0x140>(send);
      }
    }
    // fold stage 2: pairing xor7 (row_half_mirror), side bit2, n2=2
    {
      const bool hi = (lane & 4) != 0;
#pragma unroll
      for (int q = 0; q < 2; ++q) {
        const float keep = hi ? acc[q + 2] : acc[q];
        const float send = hi ? acc[q] : acc[q + 2];
        acc[q] = keep + dpp_mov<0x141>(send);
      }
    }
    // fold stage 3: pairing xor1 (quad_perm [1,0,3,2]), side bit0, n2=1
    {
      const bool hi = (lane & 1) != 0;
      const float keep = hi ? acc[1] : acc[0];
      const float send = hi ? acc[0] : acc[1];
      acc[0] = keep + dpp_mov<0xB1>(send);
    }
    // finish across unused bits {1,4,5}: all VALU-pipe lane exchanges
    float r = acc[0];
    r += dpp_mov<0x4E>(r);   // xor2: quad_perm [2,3,0,1]
    r = fold_xor16(r);       // xor16: permlane16_swap builtin
    r = fold_xor32(r);       // xor32: permlane32_swap builtin
    if (storer) *pstore = f2bf(r);   // bf16 partial (plain C, hazard-free)
    pstore += 8;
  };

  SChunk S0, S1;
  u32x2 qa = cq[0], qb = cq[384];    // chunk 0 (compiler-managed loads)
  cq += 768;
  SLOAD_CHUNK(S0, sdt, sdu); SADV(); // chunk 0 (SMEM)

#define STEP(SC, SN)                                                           \
  {                                                                            \
    const u32x2 qa_n = cq[0];                                                  \
    const u32x2 qb_n = cq[384];                                                \
    cq += 768;                                                                 \
    SWAIT(SC);                                                                 \
    SLOAD_CHUNK(SN, sdt, sdu);                                                 \
    SADV();                                                                    \
    compute_chunk(qa, qb, SC);                                                 \
    qa = qa_n;                                                                 \
    qb = qb_n;                                                                 \
  }

#pragma unroll 1
  for (int it = 0; it < 8; ++it) {   // 6 chunks/iter: S alternation closes
    STEP(S0, S1);
    STEP(S1, S0);
    STEP(S0, S1);
    STEP(S1, S0);
    STEP(S0, S1);
    STEP(S1, S0);
  }
#undef STEP
  // 48 chunks computed. Final prefetch loads are dead/DCE'd; dangling SMEM
  // prefetch writes dead SGPRs. Kernel ends here (v16 lesson).
}

// ---------------------------------------------------------------------------
// Combine + transpose: y[b,l,i] = sum_{w<6} part[w][b][i][l] + u[b,l,i]*D[i]
// part is now bf16 (halved read traffic); unpack = <<16.
// ---------------------------------------------------------------------------
__global__ __launch_bounds__(256) void combine_kernel(
    const unsigned short* __restrict__ part, const float* __restrict__ u,
    const float* __restrict__ Dv, float* __restrict__ y) {
  __shared__ float T[32][33];
  const int tx = threadIdx.x;
  const int ty0 = threadIdx.y;
  const int b = blockIdx.z;
  const int i0 = blockIdx.y * 32;
  const int l0 = blockIdx.x * 32;
#pragma unroll
  for (int r = 0; r < 4; ++r) {
    const int il = ty0 + 8 * r;
    float s = 0.f;
#pragma unroll
    for (int w = 0; w < 6; ++w) {
      const unsigned int pv =
          part[((w * B_SZ + b) * D_SZ + i0 + il) * L_SZ + l0 + tx];
      s += __uint_as_float(pv << 16);
    }
    T[il][tx] = s;
  }
  __syncthreads();
#pragma unroll
  for (int r = 0; r < 4; ++r) {
    const int ll = ty0 + 8 * r;
    const int gi = i0 + tx;
    const int off = (b * L_SZ + l0 + ll) * D_SZ + gi;
    y[off] = fmaf(u[off], Dv[gi], T[tx][ll]);
  }
}

extern "C" void kernel_launch(void* const* d_in, const int* in_sizes, int n_in,
                              void* d_out, int out_size, void* d_ws,
                              size_t ws_size, hipStream_t stream) {
  const float* x = (const float*)d_in[0];
  const float* A_log = (const float*)d_in[1];
  const float* D = (const float*)d_in[2];
  const float* dt_w = (const float*)d_in[3];
  const float* dt_b = (const float*)d_in[4];
  const float* B_w = (const float*)d_in[5];
  const float* C_w = (const float*)d_in[6];
  const float* conv_w = (const float*)d_in[7];
  const float* conv_b = (const float*)d_in[8];
  float* y = (float*)d_out;

  float* ws = (float*)d_ws;
  float* u = ws;                      // slot 0
  float* Bm = ws + TOT_ELEMS;         // slot 1
  float* dt_t = ws + 2 * TOT_ELEMS;   // slot 2  [b,i,l]
  float* dtu_t = ws + 3 * TOT_ELEMS;  // slot 3  [b,i,l]
  unsigned short* bfarea = (unsigned short*)(ws + 4 * TOT_ELEMS);
  u32x2* Cmq = (u32x2*)bfarea;                      // 589824 B (packed Cm)
  unsigned short* xdblbf = bfarea + TOT_ELEMS;      // 589824 B (overread pad)
  unsigned short* part = bfarea + 2 * TOT_ELEMS;    // 6*294912*2 B bf16

  gemm1_conv_kernel<<<dim3(12, 24), 128, 0, stream>>>(
      x, dt_w, B_w, dt_b, conv_w, conv_b, xdblbf, u, dt_t, dtu_t);
  mfma_gemm2<<<dim3(24, 24), 128, 0, stream>>>(xdblbf, B_w, C_w, Bm, Cmq);
  scan_kernel<<<4608, 64, 0, stream>>>(A_log, dt_t, dtu_t, Bm, Cmq, part);
  combine_kernel<<<dim3(L_SZ / 32, D_SZ / 32, B_SZ), dim3(32, 8), 0, stream>>>(
      part, u, D, y);
}